// Round 1
// baseline (3268.733 us; speedup 1.0000x reference)
//
#include <hip/hip_runtime.h>

namespace {
constexpr int NN = 100000;   // nodes
constexpr int NE = 1600000;  // edges
constexpr int NF = 128;      // input feats
constexpr int NC = 40;       // classes (propagated dim after algebraic reorder)
}

// deg[col[e]] += w[e]
__global__ __launch_bounds__(256) void k_deg(const int* __restrict__ col,
                                             const float* __restrict__ w,
                                             float* __restrict__ deg) {
    int e = blockIdx.x * 256 + threadIdx.x;
    if (e < NE) atomicAdd(&deg[col[e]], w[e]);
}

// deg -> deg_inv_sqrt (in place)
__global__ __launch_bounds__(256) void k_dis(float* __restrict__ deg) {
    int i = blockIdx.x * 256 + threadIdx.x;
    if (i < NN) {
        float d = deg[i];
        deg[i] = (d > 0.f) ? rsqrtf(fmaxf(d, 1e-30f)) : 0.f;
    }
}

// norm[e] = dis[row[e]] * w[e] * dis[col[e]]
__global__ __launch_bounds__(256) void k_norm(const int* __restrict__ row,
                                              const int* __restrict__ col,
                                              const float* __restrict__ w,
                                              const float* __restrict__ dis,
                                              float* __restrict__ norm) {
    int e = blockIdx.x * 256 + threadIdx.x;
    if (e < NE) norm[e] = dis[row[e]] * w[e] * dis[col[e]];
}

// H0 = x @ W : [NN,128] @ [128,40] -> [NN,40]
// block = 256 threads handles 64 nodes. W fully in LDS (20KB), x tile padded
// (+1 col) so the per-k x-row read isn't a 16-way bank conflict.
__global__ __launch_bounds__(256) void k_xw(const float* __restrict__ x,
                                            const float* __restrict__ W,
                                            float* __restrict__ h0) {
    __shared__ float Ws[NF * NC];         // 20480 B
    __shared__ float xs[64 * (NF + 1)];   // 33024 B
    int tid = threadIdx.x;
    for (int i = tid; i < NF * NC; i += 256) Ws[i] = W[i];
    int n0 = blockIdx.x * 64;
    for (int i = tid; i < 64 * NF; i += 256) {
        int n = i >> 7, k = i & (NF - 1);
        xs[n * (NF + 1) + k] = (n0 + n < NN) ? x[(n0 + n) * NF + k] : 0.f;
    }
    __syncthreads();
    int nl = tid >> 2;         // 0..63 local node
    int c0 = (tid & 3) * 10;   // 0,10,20,30 class offset
    float acc[10];
#pragma unroll
    for (int j = 0; j < 10; ++j) acc[j] = 0.f;
    const float* xr = &xs[nl * (NF + 1)];
    for (int k = 0; k < NF; ++k) {
        float xv = xr[k];
        const float* wr = &Ws[k * NC + c0];
#pragma unroll
        for (int j = 0; j < 10; ++j) acc[j] += xv * wr[j];
    }
    int n = n0 + nl;
    if (n < NN) {
        float* o = &h0[n * NC + c0];
#pragma unroll
        for (int j = 0; j < 10; ++j) o[j] = acc[j];
    }
}

// One propagation hop: hout[col[e]] += hin[row[e]] * norm[e]
// Thread per (edge, 4-float chunk): row stride is 40 floats = 160 B, so every
// 16 B chunk is float4-aligned. Gather is a vector load; scatter is 4 scalar
// device-scope atomicAdds (contiguous addresses across the 10 chunk-threads).
__global__ __launch_bounds__(256) void k_hop(const int* __restrict__ row,
                                             const int* __restrict__ col,
                                             const float* __restrict__ norm,
                                             const float* __restrict__ hin,
                                             float* __restrict__ hout) {
    int tid = blockIdx.x * 256 + threadIdx.x;
    if (tid >= NE * 10) return;
    int e = tid / 10;
    int v = tid - e * 10;
    int r = row[e], c = col[e];
    float nw = norm[e];
    float4 m = *(const float4*)(hin + r * NC + v * 4);
    float* dst = hout + c * NC + v * 4;
    atomicAdd(dst + 0, m.x * nw);
    atomicAdd(dst + 1, m.y * nw);
    atomicAdd(dst + 2, m.z * nw);
    atomicAdd(dst + 3, m.w * nw);
}

extern "C" void kernel_launch(void* const* d_in, const int* in_sizes, int n_in,
                              void* d_out, int out_size, void* d_ws, size_t ws_size,
                              hipStream_t stream) {
    const float* x  = (const float*)d_in[0];
    const int*   ei = (const int*)d_in[1];   // [2, NE] row-major
    const float* w  = (const float*)d_in[2];
    const float* W  = (const float*)d_in[3]; // [128, 40]
    const int* row = ei;
    const int* col = ei + NE;

    float* ws   = (float*)d_ws;
    float* deg  = ws;                  // NN floats (becomes deg_inv_sqrt)
    float* norm = ws + NN;             // NE floats
    float* ha   = ws + NN + NE;        // NN*NC floats (16B-aligned offset)
    float* hb   = ha + NN * NC;        // NN*NC floats
    float* out  = (float*)d_out;

    hipMemsetAsync(deg, 0, NN * sizeof(float), stream);
    k_deg<<<(NE + 255) / 256, 256, 0, stream>>>(col, w, deg);
    k_dis<<<(NN + 255) / 256, 256, 0, stream>>>(deg);
    k_norm<<<(NE + 255) / 256, 256, 0, stream>>>(row, col, w, deg, norm);

    // H0 = x @ W  (algebraic reorder: propagate 40 feats instead of 128)
    k_xw<<<(NN + 63) / 64, 256, 0, stream>>>(x, W, ha);

    const int hopBlocks = (NE * 10 + 255) / 256;  // thread per (edge, float4)
    hipMemsetAsync(hb, 0, (size_t)NN * NC * sizeof(float), stream);
    k_hop<<<hopBlocks, 256, 0, stream>>>(row, col, norm, ha, hb);
    hipMemsetAsync(ha, 0, (size_t)NN * NC * sizeof(float), stream);
    k_hop<<<hopBlocks, 256, 0, stream>>>(row, col, norm, hb, ha);
    hipMemsetAsync(out, 0, (size_t)out_size * sizeof(float), stream);
    k_hop<<<hopBlocks, 256, 0, stream>>>(row, col, norm, ha, out);
}

// Round 2
// 569.461 us; speedup vs baseline: 5.7401x; 5.7401x over previous
//
#include <hip/hip_runtime.h>

namespace {
constexpr int NN = 100000;   // nodes
constexpr int NE = 1600000;  // edges
constexpr int NF = 128;      // input feats
constexpr int NC = 40;       // classes (propagated dim after algebraic reorder)
constexpr int NB = (NN + 255) / 256;  // scan blocks = 391
}

// deg[col[e]] += w[e]; cnt[col[e]] += 1  (CSR histogram + degree in one pass)
__global__ __launch_bounds__(256) void k_degcnt(const int* __restrict__ col,
                                                const float* __restrict__ w,
                                                float* __restrict__ deg,
                                                int* __restrict__ cnt) {
    int e = blockIdx.x * 256 + threadIdx.x;
    if (e < NE) {
        int c = col[e];
        atomicAdd(&deg[c], w[e]);
        atomicAdd(&cnt[c], 1);
    }
}

// deg -> deg_inv_sqrt (in place)
__global__ __launch_bounds__(256) void k_dis(float* __restrict__ deg) {
    int i = blockIdx.x * 256 + threadIdx.x;
    if (i < NN) {
        float d = deg[i];
        deg[i] = (d > 0.f) ? rsqrtf(fmaxf(d, 1e-30f)) : 0.f;
    }
}

// -------- exclusive scan of cnt[NN] -> offs[NN+1] (3 kernels) --------
__global__ __launch_bounds__(256) void k_scan1(const int* __restrict__ cnt,
                                               int* __restrict__ offs,
                                               int* __restrict__ bsum) {
    __shared__ int s[256];
    int t = threadIdx.x, i = blockIdx.x * 256 + t;
    int v = (i < NN) ? cnt[i] : 0;
    s[t] = v;
    __syncthreads();
    for (int off = 1; off < 256; off <<= 1) {
        int add = (t >= off) ? s[t - off] : 0;
        __syncthreads();
        s[t] += add;
        __syncthreads();
    }
    if (i < NN) offs[i] = s[t] - v;             // exclusive within block
    if (t == 255) bsum[blockIdx.x] = s[255];    // block total
}

__global__ __launch_bounds__(512) void k_scan2(int* __restrict__ bsum) {
    __shared__ int s[512];
    int t = threadIdx.x;
    int v = (t < NB) ? bsum[t] : 0;
    s[t] = v;
    __syncthreads();
    for (int off = 1; off < 512; off <<= 1) {
        int add = (t >= off) ? s[t - off] : 0;
        __syncthreads();
        s[t] += add;
        __syncthreads();
    }
    if (t < NB) bsum[t] = s[t] - v;             // exclusive block offsets
}

__global__ __launch_bounds__(256) void k_scan3(int* __restrict__ offs,
                                               const int* __restrict__ bsum) {
    int i = blockIdx.x * 256 + threadIdx.x;
    if (i < NN) offs[i] += bsum[blockIdx.x];
    if (i == 0) offs[NN] = NE;                  // total is a compile-time constant
}

// scatter edges into CSR slots; fuse norm computation
__global__ __launch_bounds__(256) void k_scatter(const int* __restrict__ row,
                                                 const int* __restrict__ col,
                                                 const float* __restrict__ w,
                                                 const float* __restrict__ dis,
                                                 const int* __restrict__ offs,
                                                 int* __restrict__ cur,
                                                 int* __restrict__ rs,
                                                 float* __restrict__ ns) {
    int e = blockIdx.x * 256 + threadIdx.x;
    if (e >= NE) return;
    int r = row[e], c = col[e];
    int p = offs[c] + atomicAdd(&cur[c], 1);
    rs[p] = r;
    ns[p] = dis[r] * w[e] * dis[c];
}

// H0 = x @ W : [NN,128] @ [128,40] -> [NN,40]
__global__ __launch_bounds__(256) void k_xw(const float* __restrict__ x,
                                            const float* __restrict__ W,
                                            float* __restrict__ h0) {
    __shared__ float Ws[NF * NC];         // 20480 B
    __shared__ float xs[64 * (NF + 1)];   // 33024 B (pad kills bank conflict)
    int tid = threadIdx.x;
    for (int i = tid; i < NF * NC; i += 256) Ws[i] = W[i];
    int n0 = blockIdx.x * 64;
    for (int i = tid; i < 64 * NF; i += 256) {
        int n = i >> 7, k = i & (NF - 1);
        xs[n * (NF + 1) + k] = (n0 + n < NN) ? x[(n0 + n) * NF + k] : 0.f;
    }
    __syncthreads();
    int nl = tid >> 2;         // 0..63 local node
    int c0 = (tid & 3) * 10;   // class offset
    float acc[10];
#pragma unroll
    for (int j = 0; j < 10; ++j) acc[j] = 0.f;
    const float* xr = &xs[nl * (NF + 1)];
    for (int k = 0; k < NF; ++k) {
        float xv = xr[k];
        const float* wr = &Ws[k * NC + c0];
#pragma unroll
        for (int j = 0; j < 10; ++j) acc[j] += xv * wr[j];
    }
    int n = n0 + nl;
    if (n < NN) {
        float* o = &h0[n * NC + c0];
#pragma unroll
        for (int j = 0; j < 10; ++j) o[j] = acc[j];
    }
}

// Pull-based hop: thread per (node, float4 chunk of the 40-wide row).
// 10 consecutive threads share a node -> CSR reads hit L1, gathers of one
// h-row share cache lines, and the output write is fully coalesced.
__global__ __launch_bounds__(256) void k_hop_pull(const int* __restrict__ offs,
                                                  const int* __restrict__ rs,
                                                  const float* __restrict__ ns,
                                                  const float* __restrict__ hin,
                                                  float* __restrict__ hout) {
    int tid = blockIdx.x * 256 + threadIdx.x;
    if (tid >= NN * 10) return;
    int n = tid / 10;
    int v = tid - n * 10;
    int s0 = offs[n], s1 = offs[n + 1];
    float ax = 0.f, ay = 0.f, az = 0.f, aw = 0.f;
    for (int i = s0; i < s1; ++i) {
        int r = rs[i];
        float nw = ns[i];
        float4 m = *(const float4*)(hin + r * NC + v * 4);
        ax += m.x * nw;
        ay += m.y * nw;
        az += m.z * nw;
        aw += m.w * nw;
    }
    float4 o = {ax, ay, az, aw};
    *(float4*)(hout + n * NC + v * 4) = o;
}

extern "C" void kernel_launch(void* const* d_in, const int* in_sizes, int n_in,
                              void* d_out, int out_size, void* d_ws, size_t ws_size,
                              hipStream_t stream) {
    const float* x  = (const float*)d_in[0];
    const int*   ei = (const int*)d_in[1];   // [2, NE]
    const float* w  = (const float*)d_in[2];
    const float* W  = (const float*)d_in[3]; // [128, 40]
    const int* row = ei;
    const int* col = ei + NE;
    float* out = (float*)d_out;              // [NN, NC] — reused as ping-pong buf

    // workspace carve-up (all offsets multiples of 16 B)
    char* p = (char*)d_ws;
    float* deg  = (float*)p; p += (size_t)NN * 4;        // -> deg_inv_sqrt
    int*   cnt  = (int*)p;   p += (size_t)NN * 4;        // histogram, then cursor
    int*   offs = (int*)p;   p += (size_t)(NN + 4) * 4;  // NN+1 used
    int*   bsum = (int*)p;   p += 512 * 4;
    int*   rs   = (int*)p;   p += (size_t)NE * 4;        // CSR row ids
    float* ns   = (float*)p; p += (size_t)NE * 4;        // CSR norms
    float* ha   = (float*)p;                             // [NN, NC]

    hipMemsetAsync(deg, 0, (size_t)NN * 4, stream);
    hipMemsetAsync(cnt, 0, (size_t)NN * 4, stream);
    k_degcnt<<<(NE + 255) / 256, 256, 0, stream>>>(col, w, deg, cnt);
    k_dis<<<(NN + 255) / 256, 256, 0, stream>>>(deg);
    k_scan1<<<NB, 256, 0, stream>>>(cnt, offs, bsum);
    k_scan2<<<1, 512, 0, stream>>>(bsum);
    k_scan3<<<NB, 256, 0, stream>>>(offs, bsum);
    hipMemsetAsync(cnt, 0, (size_t)NN * 4, stream);      // reuse as scatter cursor
    k_scatter<<<(NE + 255) / 256, 256, 0, stream>>>(row, col, w, deg, offs, cnt, rs, ns);

    k_xw<<<(NN + 63) / 64, 256, 0, stream>>>(x, W, ha);  // H0 = x@W

    const int hopBlocks = (NN * 10 + 255) / 256;
    k_hop_pull<<<hopBlocks, 256, 0, stream>>>(offs, rs, ns, ha, out);   // hop 1
    k_hop_pull<<<hopBlocks, 256, 0, stream>>>(offs, rs, ns, out, ha);   // hop 2
    k_hop_pull<<<hopBlocks, 256, 0, stream>>>(offs, rs, ns, ha, out);   // hop 3
}

// Round 3
// 462.610 us; speedup vs baseline: 7.0659x; 1.2310x over previous
//
#include <hip/hip_runtime.h>

namespace {
constexpr int NN = 100000;   // nodes
constexpr int NE = 1600000;  // edges
constexpr int NF = 128;      // input feats
constexpr int NC = 40;       // classes (propagated dim after algebraic reorder)
constexpr int NB = (NN + 255) / 256;  // scan blocks = 391
constexpr float FIX = 1048576.0f;     // 2^20 fixed-point scale for deg
}

// ONE 64-bit atomic per edge: bits [63:40] = count, [39:0] = fixed-point deg.
// Returned old value's count field = this edge's rank within its col bucket
// -> k_scatter needs no atomics at all.
__global__ __launch_bounds__(256) void k_degcnt(const int* __restrict__ col,
                                                const float* __restrict__ w,
                                                unsigned long long* __restrict__ dc,
                                                int* __restrict__ rank) {
    int e = blockIdx.x * 256 + threadIdx.x;
    if (e >= NE) return;
    int c = col[e];
    unsigned long long q = (unsigned long long)(unsigned)(w[e] * FIX + 0.5f);
    unsigned long long old = atomicAdd(&dc[c], (1ull << 40) | q);
    rank[e] = (int)(old >> 40);
}

// -------- exclusive scan of counts -> offs[NN+1]; also deg -> dis --------
__global__ __launch_bounds__(256) void k_scan1(const unsigned long long* __restrict__ dc,
                                               int* __restrict__ offs,
                                               int* __restrict__ bsum,
                                               float* __restrict__ dis) {
    __shared__ int s[256];
    int t = threadIdx.x, i = blockIdx.x * 256 + t;
    unsigned long long p = (i < NN) ? dc[i] : 0ull;
    int v = (int)(p >> 40);
    if (i < NN) {
        float d = (float)(p & ((1ull << 40) - 1)) * (1.0f / FIX);
        dis[i] = (d > 0.f) ? rsqrtf(d) : 0.f;
    }
    s[t] = v;
    __syncthreads();
    for (int off = 1; off < 256; off <<= 1) {
        int add = (t >= off) ? s[t - off] : 0;
        __syncthreads();
        s[t] += add;
        __syncthreads();
    }
    if (i < NN) offs[i] = s[t] - v;             // exclusive within block
    if (t == 255) bsum[blockIdx.x] = s[255];    // block total
}

__global__ __launch_bounds__(512) void k_scan2(int* __restrict__ bsum) {
    __shared__ int s[512];
    int t = threadIdx.x;
    int v = (t < NB) ? bsum[t] : 0;
    s[t] = v;
    __syncthreads();
    for (int off = 1; off < 512; off <<= 1) {
        int add = (t >= off) ? s[t - off] : 0;
        __syncthreads();
        s[t] += add;
        __syncthreads();
    }
    if (t < NB) bsum[t] = s[t] - v;             // exclusive block offsets
}

__global__ __launch_bounds__(256) void k_scan3(int* __restrict__ offs,
                                               const int* __restrict__ bsum) {
    int i = blockIdx.x * 256 + threadIdx.x;
    if (i < NN) offs[i] += bsum[blockIdx.x];
    if (i == 0) offs[NN] = NE;                  // total is compile-time constant
}

// CSR scatter, atomic-free: slot = offs[col] + rank (rank captured in k_degcnt)
__global__ __launch_bounds__(256) void k_scatter(const int* __restrict__ row,
                                                 const int* __restrict__ col,
                                                 const float* __restrict__ w,
                                                 const float* __restrict__ dis,
                                                 const int* __restrict__ offs,
                                                 const int* __restrict__ rank,
                                                 int* __restrict__ rs,
                                                 float* __restrict__ ns) {
    int e = blockIdx.x * 256 + threadIdx.x;
    if (e >= NE) return;
    int r = row[e], c = col[e];
    int p = offs[c] + rank[e];
    rs[p] = r;
    ns[p] = dis[r] * w[e] * dis[c];
}

// H0 = x @ W : [NN,128] @ [128,40] -> [NN,40]
__global__ __launch_bounds__(256) void k_xw(const float* __restrict__ x,
                                            const float* __restrict__ W,
                                            float* __restrict__ h0) {
    __shared__ float Ws[NF * NC];         // 20480 B
    __shared__ float xs[64 * (NF + 1)];   // 33024 B (pad kills bank conflict)
    int tid = threadIdx.x;
    for (int i = tid; i < NF * NC; i += 256) Ws[i] = W[i];
    int n0 = blockIdx.x * 64;
    for (int i = tid; i < 64 * NF; i += 256) {
        int n = i >> 7, k = i & (NF - 1);
        xs[n * (NF + 1) + k] = (n0 + n < NN) ? x[(n0 + n) * NF + k] : 0.f;
    }
    __syncthreads();
    int nl = tid >> 2;         // 0..63 local node
    int c0 = (tid & 3) * 10;   // class offset
    float acc[10];
#pragma unroll
    for (int j = 0; j < 10; ++j) acc[j] = 0.f;
    const float* xr = &xs[nl * (NF + 1)];
    for (int k = 0; k < NF; ++k) {
        float xv = xr[k];
        const float* wr = &Ws[k * NC + c0];
#pragma unroll
        for (int j = 0; j < 10; ++j) acc[j] += xv * wr[j];
    }
    int n = n0 + nl;
    if (n < NN) {
        float* o = &h0[n * NC + c0];
#pragma unroll
        for (int j = 0; j < 10; ++j) o[j] = acc[j];
    }
}

// Pull-based hop: thread per (node, float4 chunk of the 40-wide row).
__global__ __launch_bounds__(256) void k_hop_pull(const int* __restrict__ offs,
                                                  const int* __restrict__ rs,
                                                  const float* __restrict__ ns,
                                                  const float* __restrict__ hin,
                                                  float* __restrict__ hout) {
    int tid = blockIdx.x * 256 + threadIdx.x;
    if (tid >= NN * 10) return;
    int n = tid / 10;
    int v = tid - n * 10;
    int s0 = offs[n], s1 = offs[n + 1];
    float ax = 0.f, ay = 0.f, az = 0.f, aw = 0.f;
    for (int i = s0; i < s1; ++i) {
        int r = rs[i];
        float nw = ns[i];
        float4 m = *(const float4*)(hin + r * NC + v * 4);
        ax += m.x * nw;
        ay += m.y * nw;
        az += m.z * nw;
        aw += m.w * nw;
    }
    float4 o = {ax, ay, az, aw};
    *(float4*)(hout + n * NC + v * 4) = o;
}

extern "C" void kernel_launch(void* const* d_in, const int* in_sizes, int n_in,
                              void* d_out, int out_size, void* d_ws, size_t ws_size,
                              hipStream_t stream) {
    const float* x  = (const float*)d_in[0];
    const int*   ei = (const int*)d_in[1];   // [2, NE]
    const float* w  = (const float*)d_in[2];
    const float* W  = (const float*)d_in[3]; // [128, 40]
    const int* row = ei;
    const int* col = ei + NE;
    float* out = (float*)d_out;              // [NN, NC] — doubles as ping-pong buf

    // workspace carve-up (all offsets 16B-aligned)
    char* p = (char*)d_ws;
    unsigned long long* dc = (unsigned long long*)p; p += (size_t)NN * 8;  // packed cnt|deg
    float* dis  = (float*)p; p += (size_t)NN * 4;
    int*   offs = (int*)p;   p += (size_t)(NN + 4) * 4;
    int*   bsum = (int*)p;   p += 512 * 4;
    int*   rs   = (int*)p;   p += (size_t)NE * 4;        // CSR row ids
    float* ns   = (float*)p; p += (size_t)NE * 4;        // CSR norms
    int*   rank = (int*)p;                               // dead after k_scatter...
    float* ha   = (float*)p;                             // ...then reused as [NN,NC]

    hipMemsetAsync(dc, 0, (size_t)NN * 8, stream);
    k_degcnt<<<(NE + 255) / 256, 256, 0, stream>>>(col, w, dc, rank);
    k_scan1<<<NB, 256, 0, stream>>>(dc, offs, bsum, dis);
    k_scan2<<<1, 512, 0, stream>>>(bsum);
    k_scan3<<<NB, 256, 0, stream>>>(offs, bsum);
    k_scatter<<<(NE + 255) / 256, 256, 0, stream>>>(row, col, w, dis, offs, rank, rs, ns);

    k_xw<<<(NN + 63) / 64, 256, 0, stream>>>(x, W, ha);  // H0 = x@W

    const int hopBlocks = (NN * 10 + 255) / 256;
    k_hop_pull<<<hopBlocks, 256, 0, stream>>>(offs, rs, ns, ha, out);   // hop 1
    k_hop_pull<<<hopBlocks, 256, 0, stream>>>(offs, rs, ns, out, ha);   // hop 2
    k_hop_pull<<<hopBlocks, 256, 0, stream>>>(offs, rs, ns, ha, out);   // hop 3
}

// Round 4
// 415.677 us; speedup vs baseline: 7.8636x; 1.1129x over previous
//
#include <hip/hip_runtime.h>

namespace {
constexpr int NN = 100000;   // nodes
constexpr int NE = 1600000;  // edges
constexpr int NF = 128;      // input feats
constexpr int NC = 40;       // classes (propagated dim after algebraic reorder)
constexpr int NB = (NN + 255) / 256;  // scan blocks = 391
constexpr float FIX = 1048576.0f;     // 2^20 fixed-point scale for deg
}

// ONE 64-bit atomic per edge: bits [63:40] = count, [39:0] = fixed-point deg.
// Returned old value's count field = this edge's rank within its col bucket.
__global__ __launch_bounds__(256) void k_degcnt(const int* __restrict__ col,
                                                const float* __restrict__ w,
                                                unsigned long long* __restrict__ dc,
                                                int* __restrict__ rank) {
    int e = blockIdx.x * 256 + threadIdx.x;
    if (e >= NE) return;
    int c = col[e];
    unsigned long long q = (unsigned long long)(unsigned)(w[e] * FIX + 0.5f);
    unsigned long long old = atomicAdd(&dc[c], (1ull << 40) | q);
    rank[e] = (int)(old >> 40);
}

// -------- exclusive scan of counts -> offs[NN+1]; also deg -> dis --------
__global__ __launch_bounds__(256) void k_scan1(const unsigned long long* __restrict__ dc,
                                               int* __restrict__ offs,
                                               int* __restrict__ bsum,
                                               float* __restrict__ dis) {
    __shared__ int s[256];
    int t = threadIdx.x, i = blockIdx.x * 256 + t;
    unsigned long long p = (i < NN) ? dc[i] : 0ull;
    int v = (int)(p >> 40);
    if (i < NN) {
        float d = (float)(p & ((1ull << 40) - 1)) * (1.0f / FIX);
        dis[i] = (d > 0.f) ? rsqrtf(d) : 0.f;
    }
    s[t] = v;
    __syncthreads();
    for (int off = 1; off < 256; off <<= 1) {
        int add = (t >= off) ? s[t - off] : 0;
        __syncthreads();
        s[t] += add;
        __syncthreads();
    }
    if (i < NN) offs[i] = s[t] - v;             // exclusive within block
    if (t == 255) bsum[blockIdx.x] = s[255];    // block total
}

__global__ __launch_bounds__(512) void k_scan2(int* __restrict__ bsum) {
    __shared__ int s[512];
    int t = threadIdx.x;
    int v = (t < NB) ? bsum[t] : 0;
    s[t] = v;
    __syncthreads();
    for (int off = 1; off < 512; off <<= 1) {
        int add = (t >= off) ? s[t - off] : 0;
        __syncthreads();
        s[t] += add;
        __syncthreads();
    }
    if (t < NB) bsum[t] = s[t] - v;             // exclusive block offsets
}

__global__ __launch_bounds__(256) void k_scan3(int* __restrict__ offs,
                                               const int* __restrict__ bsum) {
    int i = blockIdx.x * 256 + threadIdx.x;
    if (i < NN) offs[i] += bsum[blockIdx.x];
    if (i == 0) offs[NN] = NE;                  // total is compile-time constant
}

// CSR scatter, atomic-free. Fused {row, norm} int2 store: ONE scattered
// cacheline per edge instead of two (rs/ns split cost 106 MB WRITE_SIZE).
__global__ __launch_bounds__(256) void k_scatter(const int* __restrict__ row,
                                                 const int* __restrict__ col,
                                                 const float* __restrict__ w,
                                                 const float* __restrict__ dis,
                                                 const int* __restrict__ offs,
                                                 const int* __restrict__ rank,
                                                 int2* __restrict__ pair) {
    int e = blockIdx.x * 256 + threadIdx.x;
    if (e >= NE) return;
    int r = row[e], c = col[e];
    int p = offs[c] + rank[e];
    int2 pr;
    pr.x = r;
    pr.y = __float_as_int(dis[r] * w[e] * dis[c]);
    pair[p] = pr;
}

// H0 = x @ W : [NN,128] @ [128,40] -> [NN,40]
// No LDS: thread per node, 40 accumulators. W is indexed block-uniformly ->
// scalar (s_load) or L1-broadcast loads; x row read as 32 x dwordx4.
// (R3 version was LDS-read-bound: 11 ds_read_b32 per 10 FMA, 25% occupancy.)
__global__ __launch_bounds__(256) void k_xw(const float* __restrict__ x,
                                            const float* __restrict__ W,
                                            float* __restrict__ h0) {
    int n = blockIdx.x * 256 + threadIdx.x;
    if (n >= NN) return;
    const float4* xr = (const float4*)(x + (size_t)n * NF);  // 32 float4
    const float4* W4 = (const float4*)W;                     // row k = 10 float4
    float acc[NC];
#pragma unroll
    for (int j = 0; j < NC; ++j) acc[j] = 0.f;
    for (int k4 = 0; k4 < NF / 4; ++k4) {
        float4 xv = xr[k4];
#pragma unroll
        for (int kk = 0; kk < 4; ++kk) {
            float xk = (kk == 0) ? xv.x : (kk == 1) ? xv.y : (kk == 2) ? xv.z : xv.w;
            int k = k4 * 4 + kk;
#pragma unroll
            for (int j4 = 0; j4 < 10; ++j4) {
                float4 wv = W4[k * 10 + j4];   // block-uniform address
                acc[j4 * 4 + 0] += xk * wv.x;
                acc[j4 * 4 + 1] += xk * wv.y;
                acc[j4 * 4 + 2] += xk * wv.z;
                acc[j4 * 4 + 3] += xk * wv.w;
            }
        }
    }
    float4* o = (float4*)(h0 + (size_t)n * NC);
#pragma unroll
    for (int j4 = 0; j4 < 10; ++j4) {
        float4 v = {acc[j4 * 4 + 0], acc[j4 * 4 + 1], acc[j4 * 4 + 2], acc[j4 * 4 + 3]};
        o[j4] = v;
    }
}

// Pull-based hop: thread per (node, float4 chunk of the 40-wide row).
// Fused {row,norm} b64 loads; edge loop unrolled x2 for gather MLP.
__global__ __launch_bounds__(256) void k_hop_pull(const int* __restrict__ offs,
                                                  const int2* __restrict__ pair,
                                                  const float* __restrict__ hin,
                                                  float* __restrict__ hout) {
    int tid = blockIdx.x * 256 + threadIdx.x;
    if (tid >= NN * 10) return;
    int n = tid / 10;
    int v = tid - n * 10;
    int s0 = offs[n], s1 = offs[n + 1];
    float ax = 0.f, ay = 0.f, az = 0.f, aw = 0.f;
    int i = s0;
    for (; i + 2 <= s1; i += 2) {
        int2 p0 = pair[i];
        int2 p1 = pair[i + 1];
        float4 m0 = *(const float4*)(hin + (size_t)p0.x * NC + v * 4);
        float4 m1 = *(const float4*)(hin + (size_t)p1.x * NC + v * 4);
        float w0 = __int_as_float(p0.y);
        float w1 = __int_as_float(p1.y);
        ax += m0.x * w0; ay += m0.y * w0; az += m0.z * w0; aw += m0.w * w0;
        ax += m1.x * w1; ay += m1.y * w1; az += m1.z * w1; aw += m1.w * w1;
    }
    if (i < s1) {
        int2 p0 = pair[i];
        float4 m0 = *(const float4*)(hin + (size_t)p0.x * NC + v * 4);
        float w0 = __int_as_float(p0.y);
        ax += m0.x * w0; ay += m0.y * w0; az += m0.z * w0; aw += m0.w * w0;
    }
    float4 o = {ax, ay, az, aw};
    *(float4*)(hout + (size_t)n * NC + v * 4) = o;
}

extern "C" void kernel_launch(void* const* d_in, const int* in_sizes, int n_in,
                              void* d_out, int out_size, void* d_ws, size_t ws_size,
                              hipStream_t stream) {
    const float* x  = (const float*)d_in[0];
    const int*   ei = (const int*)d_in[1];   // [2, NE]
    const float* w  = (const float*)d_in[2];
    const float* W  = (const float*)d_in[3]; // [128, 40]
    const int* row = ei;
    const int* col = ei + NE;
    float* out = (float*)d_out;              // [NN, NC] — doubles as ping-pong buf

    // workspace carve-up (all offsets 16B-aligned)
    char* p = (char*)d_ws;
    unsigned long long* dc = (unsigned long long*)p; p += (size_t)NN * 8;  // packed cnt|deg
    float* dis  = (float*)p; p += (size_t)NN * 4;
    int*   offs = (int*)p;   p += (size_t)(NN + 4) * 4;
    int*   bsum = (int*)p;   p += 512 * 4;
    int2*  pair = (int2*)p;  p += (size_t)NE * 8;        // CSR {row, norm}
    int*   rank = (int*)p;                               // dead after k_scatter...
    float* ha   = (float*)p;                             // ...then reused as [NN,NC]

    hipMemsetAsync(dc, 0, (size_t)NN * 8, stream);
    k_degcnt<<<(NE + 255) / 256, 256, 0, stream>>>(col, w, dc, rank);
    k_scan1<<<NB, 256, 0, stream>>>(dc, offs, bsum, dis);
    k_scan2<<<1, 512, 0, stream>>>(bsum);
    k_scan3<<<NB, 256, 0, stream>>>(offs, bsum);
    k_scatter<<<(NE + 255) / 256, 256, 0, stream>>>(row, col, w, dis, offs, rank, pair);

    k_xw<<<(NN + 255) / 256, 256, 0, stream>>>(x, W, ha);  // H0 = x@W

    const int hopBlocks = (NN * 10 + 255) / 256;
    k_hop_pull<<<hopBlocks, 256, 0, stream>>>(offs, pair, ha, out);   // hop 1
    k_hop_pull<<<hopBlocks, 256, 0, stream>>>(offs, pair, out, ha);   // hop 2
    k_hop_pull<<<hopBlocks, 256, 0, stream>>>(offs, pair, ha, out);   // hop 3
}